// Round 5
// baseline (209.517 us; speedup 1.0000x reference)
//
#include <hip/hip_runtime.h>
#include <hip/hip_bf16.h>

#define PP     512
#define KK     64
#define BB     32
#define LLEN   2048
#define NPOS   (BB * LLEN)   // 65536

typedef __attribute__((ext_vector_type(8)))  short short8;
typedef __attribute__((ext_vector_type(16))) float float16;

__device__ inline unsigned int pack_bf2(float lo, float hi) {
    __hip_bfloat162 h = __float22bfloat162_rn(make_float2(lo, hi));
    unsigned int u;
    __builtin_memcpy(&u, &h, 4);
    return u;   // low 16 = lo, high 16 = hi
}
__device__ inline float bf_lo(unsigned int v) { return __uint_as_float(v << 16); }
__device__ inline float bf_hi(unsigned int v) { return __uint_as_float(v & 0xffff0000u); }

// ---------------------------------------------------------------------------
// K1: unified B-operand fragments, 128 columns: n<64 -> l_hat[n], n>=64 -> f2w[n-64].
// Layout (ushort): Bu[((p>>3)*128 + n)*8 + (p&7)] = bf16(src[n][p] * inv)
// ---------------------------------------------------------------------------
__global__ void k1_prep(const float* __restrict__ C, const float* __restrict__ f2w,
                        ushort* __restrict__ Bu) {
    const int n = blockIdx.x;            // 0..127
    const float* src = (n < 64) ? (C + n * PP) : (f2w + (n - 64) * PP);
    const int t = threadIdx.x;
    float v0 = src[t];
    float v1 = src[t + 256];
    __shared__ float red[256];
    red[t] = v0 * v0 + v1 * v1;
    __syncthreads();
    for (int s = 128; s > 0; s >>= 1) {
        if (t < s) red[t] += red[t + s];
        __syncthreads();
    }
    const float inv = (n < 64) ? rsqrtf(red[0]) : 1.f;
    Bu[(((t >> 3)       * 128 + n) << 3) + (t & 7)] = (ushort)(pack_bf2(v0 * inv, 0.f) & 0xffffu);
    Bu[((((t + 256) >> 3)) * 128 + n) * 8 + (t & 7)] = (ushort)(pack_bf2(v1 * inv, 0.f) & 0xffffu);
}

// ---------------------------------------------------------------------------
// K2: MFMA GEMM, 64 positions x 128 n-cols, K=512 in 4 chunks of 128,
// with register prefetch of the next chunk's V slices (hides gather latency
// behind the MFMA phase). LDS ~49.7KB -> 3 blocks/CU.
// ---------------------------------------------------------------------------
__launch_bounds__(256, 3)
__global__ void k2_gemm(const int* __restrict__ x, const float* __restrict__ V,
                        const uint4* __restrict__ Bu4,
                        unsigned int* __restrict__ Gt2, unsigned int* __restrict__ E2p) {
    __shared__ uint4 sA[64 * 16];    // 16 KB
    __shared__ uint4 sB[16 * 128];   // 32 KB
    __shared__ int   stok[64];
    __shared__ float rnorm[64];

    const int tid  = threadIdx.x;
    const int lane = tid & 63;
    const int wv   = tid >> 6;
    const int f    = tid & 15;
    const int mrow = tid >> 4;       // 0..15, rows mrow, mrow+16, mrow+32, mrow+48

    if (tid < 64) stok[tid] = x[blockIdx.x * 64 + tid];
    __syncthreads();

    float16 acc0, acc1;
#pragma unroll
    for (int i = 0; i < 16; ++i) { acc0[i] = 0.f; acc1[i] = 0.f; }
    float nacc[4];
#pragma unroll
    for (int i = 0; i < 4; ++i) nacc[i] = 0.f;

    const int mt = (wv & 1) * 32;
    const int nh = (wv >> 1) * 64;

    // ---- prologue: prefetch kc=0 A-slices into registers ----
    float4 pa[4][2];
#pragma unroll
    for (int i = 0; i < 4; ++i) {
        const float* src = V + (size_t)stok[mrow + i * 16] * PP + f * 8;
        pa[i][0] = ((const float4*)src)[0];
        pa[i][1] = ((const float4*)src)[1];
    }

    for (int kc = 0; kc < 4; ++kc) {
        __syncthreads();                 // prior MFMA done reading LDS
        // ---- pack prefetched A regs -> LDS, fp32 norms ----
#pragma unroll
        for (int i = 0; i < 4; ++i) {
            const int m = mrow + i * 16;
            const float4 a = pa[i][0];
            const float4 b = pa[i][1];
            uint4 wq;
            wq.x = pack_bf2(a.x, a.y); wq.y = pack_bf2(a.z, a.w);
            wq.z = pack_bf2(b.x, b.y); wq.w = pack_bf2(b.z, b.w);
            sA[m * 16 + (f ^ (m & 7))] = wq;
            float s2 = 0.f;
            s2 = fmaf(a.x, a.x, s2); s2 = fmaf(a.y, a.y, s2);
            s2 = fmaf(a.z, a.z, s2); s2 = fmaf(a.w, a.w, s2);
            s2 = fmaf(b.x, b.x, s2); s2 = fmaf(b.y, b.y, s2);
            s2 = fmaf(b.z, b.z, s2); s2 = fmaf(b.w, b.w, s2);
            nacc[i] += s2;
        }
        // ---- stage B chunk ----
#pragma unroll
        for (int i = 0; i < 8; ++i)
            sB[i * 256 + tid] = Bu4[kc * 2048 + i * 256 + tid];

        // ---- issue next chunk's A loads (consumed next iteration) ----
        if (kc < 3) {
#pragma unroll
            for (int i = 0; i < 4; ++i) {
                const float* src = V + (size_t)stok[mrow + i * 16] * PP + (kc + 1) * 128 + f * 8;
                pa[i][0] = ((const float4*)src)[0];
                pa[i][1] = ((const float4*)src)[1];
            }
        } else {
#pragma unroll
            for (int i = 0; i < 4; ++i) {
                float r = nacc[i];
                r += __shfl_down(r, 8, 16);
                r += __shfl_down(r, 4, 16);
                r += __shfl_down(r, 2, 16);
                r += __shfl_down(r, 1, 16);
                if (f == 0) rnorm[mrow + i * 16] = rsqrtf(r);
            }
        }
        __syncthreads();

        // ---- MFMA: 8 K-steps of 16 ----
#pragma unroll
        for (int kb = 0; kb < 8; ++kb) {
            const int ff = kb * 2 + (lane >> 5);
            const int mq = mt + (lane & 31);
            const uint4 av = sA[mq * 16 + (ff ^ (mq & 7))];
            const uint4 b0 = sB[ff * 128 + nh + (lane & 31)];
            const uint4 b1 = sB[ff * 128 + nh + 32 + (lane & 31)];
            short8 a8, t0, t1;
            __builtin_memcpy(&a8, &av, 16);
            __builtin_memcpy(&t0, &b0, 16);
            __builtin_memcpy(&t1, &b1, 16);
            acc0 = __builtin_amdgcn_mfma_f32_32x32x16_bf16(a8, t0, acc0, 0, 0, 0);
            acc1 = __builtin_amdgcn_mfma_f32_32x32x16_bf16(a8, t1, acc1, 0, 0, 0);
        }
    }

    // ---- epilogue ----
    const size_t posBase = (size_t)blockIdx.x * 64;
#pragma unroll
    for (int reg = 0; reg < 16; ++reg) {
        const int r  = (reg & 3) + 8 * (reg >> 2) + 4 * (lane >> 5);
        const int mq = mt + r;
        const size_t p = posBase + mq;
        if (wv < 2) {
            const float rn = rnorm[mq];
            Gt2[p * 32 + (lane & 31)] = pack_bf2(acc0[reg] * rn, acc1[reg] * rn);
        } else {
            E2p[p * 32 + (lane & 31)] = pack_bf2(acc0[reg], acc1[reg]);
        }
    }
}

// ---------------------------------------------------------------------------
// K3: fused conv-max + online-softmax partial pooling.
// Block = (b, chunk of 128 l), 512 blocks.
//   m[l]  = max_k relu(conv11(G)[l]+f1b[k])
//   mx_c  = max_l m ; se_c = sum_l exp(m-mx_c)
//   P_c[k]= sum_l exp(m[l]-mx_c) * E2[l][k]
// pool[blk][0..63]=P_c, [64]=mx_c, [65]=se_c   (stride 68)
// ---------------------------------------------------------------------------
__global__ void k3_convpool(const unsigned int* __restrict__ Gt2,
                            const unsigned int* __restrict__ E2p,
                            const float* __restrict__ f1w, const float* __restrict__ f1b,
                            float* __restrict__ pool) {
    __shared__ unsigned int sT[138 * 33];
    __shared__ float smv[128];
    __shared__ float sp[128];
    __shared__ float sscal[2];
    __shared__ float sred[8][64];

    const int b  = blockIdx.x >> 4;
    const int l0 = (blockIdx.x & 15) * 128;
    const int t  = threadIdx.x;

    for (int idx = t; idx < 138 * 32; idx += 256) {
        const int row = idx >> 5, col = idx & 31;
        const int gl = l0 - 5 + row;
        sT[row * 33 + col] = (gl >= 0 && gl < LLEN)
            ? Gt2[((size_t)b * LLEN + gl) * 32 + col] : 0u;
    }
    __syncthreads();

    float w[11];
#pragma unroll
    for (int j = 0; j < 11; ++j) w[j] = f1w[j];
    const int j = t & 31;
    const int h = t >> 5;
    const float bias0 = f1b[j], bias1 = f1b[j + 32];
#pragma unroll 2
    for (int i = 0; i < 16; ++i) {
        const int lr = i * 8 + h;
        float u0 = 0.f, u1 = 0.f;
#pragma unroll
        for (int tap = 0; tap < 11; ++tap) {
            const unsigned int v = sT[(lr + tap) * 33 + j];
            u0 = fmaf(bf_lo(v), w[tap], u0);
            u1 = fmaf(bf_hi(v), w[tap], u1);
        }
        float m = fmaxf(fmaxf(u0 + bias0, 0.f), fmaxf(u1 + bias1, 0.f));
#pragma unroll
        for (int off = 16; off > 0; off >>= 1)
            m = fmaxf(m, __shfl_xor(m, off, 64));
        if (j == 0) smv[lr] = m;
    }
    __syncthreads();

    // tile max
    if (t < 64) {
        float v = fmaxf(smv[t], smv[t + 64]);
#pragma unroll
        for (int off = 32; off > 0; off >>= 1)
            v = fmaxf(v, __shfl_xor(v, off, 64));
        if (t == 0) sscal[0] = v;
    }
    __syncthreads();
    const float mx = sscal[0];
    if (t < 128) sp[t] = __expf(smv[t] - mx);
    __syncthreads();
    if (t < 64) {
        float s = sp[t] + sp[t + 64];
#pragma unroll
        for (int off = 32; off > 0; off >>= 1)
            s += __shfl_xor(s, off, 64);
        if (t == 0) sscal[1] = s;
    }

    // partial pooling over the 128 l of this tile
    float a0 = 0.f, a1 = 0.f;
#pragma unroll 4
    for (int i = 0; i < 16; ++i) {
        const int l = i * 8 + h;
        const float wgt = sp[l];
        const unsigned int e = E2p[((size_t)b * LLEN + l0 + l) * 32 + j];
        a0 = fmaf(wgt, bf_lo(e), a0);
        a1 = fmaf(wgt, bf_hi(e), a1);
    }
    sred[h][j]      = a0;
    sred[h][j + 32] = a1;
    __syncthreads();
    if (t < 64) {
        float r = 0.f;
#pragma unroll
        for (int hh = 0; hh < 8; ++hh) r += sred[hh][t];
        float* dst = pool + (size_t)blockIdx.x * 68;
        dst[t] = r;
        if (t == 0) { dst[64] = mx; dst[65] = sscal[1]; }
    }
}

// ---------------------------------------------------------------------------
// K6: combine 16 chunk-partials per b with online-softmax rescale + head bias.
// ---------------------------------------------------------------------------
__global__ void k6_final(const float* __restrict__ pool, const float* __restrict__ f2b,
                         float* __restrict__ out) {
    const int b = blockIdx.x;
    const int k = threadIdx.x;   // 64 threads
    float M = -1e30f;
#pragma unroll
    for (int c = 0; c < 16; ++c)
        M = fmaxf(M, pool[(size_t)(b * 16 + c) * 68 + 64]);
    float tot = 0.f, num = 0.f;
#pragma unroll
    for (int c = 0; c < 16; ++c) {
        const float* pc = pool + (size_t)(b * 16 + c) * 68;
        const float sc = __expf(pc[64] - M);
        tot = fmaf(sc, pc[65], tot);
        num = fmaf(sc, pc[k], num);
    }
    out[b * KK + k] = (num / tot) * (1.f / 2048.f) + f2b[k];
}

extern "C" void kernel_launch(void* const* d_in, const int* in_sizes, int n_in,
                              void* d_out, int out_size, void* d_ws, size_t ws_size,
                              hipStream_t stream) {
    const int*   x   = (const int*)d_in[0];
    const float* V   = (const float*)d_in[1];
    const float* C   = (const float*)d_in[2];
    const float* f1w = (const float*)d_in[3];
    const float* f1b = (const float*)d_in[4];
    const float* f2w = (const float*)d_in[5];
    const float* f2b = (const float*)d_in[6];
    float* out = (float*)d_out;

    float* ws = (float*)d_ws;
    ushort* Bu = (ushort*)ws;                             // 64K ushort (32768 fl... occupies 16384 floats)
    unsigned int* Gt2 = (unsigned int*)(ws + 32768);      // NPOS*32 uints
    unsigned int* E2p = Gt2 + (size_t)NPOS * 32;          // NPOS*32 uints
    float* pool = (float*)(E2p + (size_t)NPOS * 32);      // 512*68 floats

    k1_prep    <<<128, 256, 0, stream>>>(C, f2w, Bu);
    k2_gemm    <<<NPOS / 64, 256, 0, stream>>>(x, V, (const uint4*)Bu, Gt2, E2p);
    k3_convpool<<<BB * 16, 256, 0, stream>>>(Gt2, E2p, f1w, f1b, pool);
    k6_final   <<<BB, 64, 0, stream>>>(pool, f2b, out);
}

// Round 6
// 198.773 us; speedup vs baseline: 1.0540x; 1.0540x over previous
//
#include <hip/hip_runtime.h>
#include <hip/hip_bf16.h>

#define PP     512
#define KK     64
#define BB     32
#define LLEN   2048
#define NPOS   (BB * LLEN)   // 65536

typedef __attribute__((ext_vector_type(8)))  short short8;
typedef __attribute__((ext_vector_type(16))) float float16;

__device__ inline unsigned int pack_bf2(float lo, float hi) {
    __hip_bfloat162 h = __float22bfloat162_rn(make_float2(lo, hi));
    unsigned int u;
    __builtin_memcpy(&u, &h, 4);
    return u;   // low 16 = lo, high 16 = hi
}
__device__ inline float bf_lo(unsigned int v) { return __uint_as_float(v << 16); }
__device__ inline float bf_hi(unsigned int v) { return __uint_as_float(v & 0xffff0000u); }

// ---------------------------------------------------------------------------
// K1: unified B-operand fragments, 128 columns: n<64 -> l_hat[n], n>=64 -> f2w[n-64].
// Layout (ushort): Bu[((p>>3)*128 + n)*8 + (p&7)] = bf16(src[n][p] * inv)
// As uint4: Bu4[(p>>3)*128 + n] = fragment (8 bf16) for column n, k-block p>>3.
// ---------------------------------------------------------------------------
__global__ void k1_prep(const float* __restrict__ C, const float* __restrict__ f2w,
                        ushort* __restrict__ Bu) {
    const int n = blockIdx.x;            // 0..127
    const float* src = (n < 64) ? (C + n * PP) : (f2w + (n - 64) * PP);
    const int t = threadIdx.x;
    float v0 = src[t];
    float v1 = src[t + 256];
    __shared__ float red[256];
    red[t] = v0 * v0 + v1 * v1;
    __syncthreads();
    for (int s = 128; s > 0; s >>= 1) {
        if (t < s) red[t] += red[t + s];
        __syncthreads();
    }
    const float inv = (n < 64) ? rsqrtf(red[0]) : 1.f;
    Bu[(((t >> 3)       * 128 + n) << 3) + (t & 7)] = (ushort)(pack_bf2(v0 * inv, 0.f) & 0xffffu);
    Bu[((((t + 256) >> 3)) * 128 + n) * 8 + (t & 7)] = (ushort)(pack_bf2(v1 * inv, 0.f) & 0xffffu);
}

// ---------------------------------------------------------------------------
// K2: MFMA GEMM, 64 positions x 128 n-cols, K=512 in 4 chunks of 128.
// A staged in LDS (16KB, xor-swizzled); B read DIRECTLY from global (L1/L2-hot,
// identical for all blocks) -- no sB, so all 4 blocks/CU are co-resident
// (16 waves/CU) to hide the V-row gather latency.
// ---------------------------------------------------------------------------
__launch_bounds__(256)
__global__ void k2_gemm(const int* __restrict__ x, const float* __restrict__ V,
                        const uint4* __restrict__ Bu4,
                        unsigned int* __restrict__ Gt2, unsigned int* __restrict__ E2p) {
    __shared__ uint4 sA[64 * 16];    // 16 KB
    __shared__ int   stok[64];
    __shared__ float rnorm[64];

    const int tid  = threadIdx.x;
    const int lane = tid & 63;
    const int wv   = tid >> 6;
    const int f    = tid & 15;
    const int mrow = tid >> 4;       // 0..15 -> rows mrow + 16i

    if (tid < 64) stok[tid] = x[blockIdx.x * 64 + tid];
    __syncthreads();

    float16 acc0, acc1;
#pragma unroll
    for (int i = 0; i < 16; ++i) { acc0[i] = 0.f; acc1[i] = 0.f; }
    float nacc[4];
#pragma unroll
    for (int i = 0; i < 4; ++i) nacc[i] = 0.f;

    const int mt = (wv & 1) * 32;    // m-tile
    const int nh = (wv >> 1) * 64;   // n-half: waves 0,1 -> cos; waves 2,3 -> E2

    // prologue: prefetch kc=0 A-slices
    float4 pa[4][2];
#pragma unroll
    for (int i = 0; i < 4; ++i) {
        const float* src = V + (size_t)stok[mrow + i * 16] * PP + f * 8;
        pa[i][0] = ((const float4*)src)[0];
        pa[i][1] = ((const float4*)src)[1];
    }

    for (int kc = 0; kc < 4; ++kc) {
        __syncthreads();
        // ---- pack prefetched A -> LDS, fp32 norms ----
#pragma unroll
        for (int i = 0; i < 4; ++i) {
            const int m = mrow + i * 16;
            const float4 a = pa[i][0];
            const float4 b = pa[i][1];
            uint4 wq;
            wq.x = pack_bf2(a.x, a.y); wq.y = pack_bf2(a.z, a.w);
            wq.z = pack_bf2(b.x, b.y); wq.w = pack_bf2(b.z, b.w);
            sA[m * 16 + (f ^ (m & 7))] = wq;
            float s2 = 0.f;
            s2 = fmaf(a.x, a.x, s2); s2 = fmaf(a.y, a.y, s2);
            s2 = fmaf(a.z, a.z, s2); s2 = fmaf(a.w, a.w, s2);
            s2 = fmaf(b.x, b.x, s2); s2 = fmaf(b.y, b.y, s2);
            s2 = fmaf(b.z, b.z, s2); s2 = fmaf(b.w, b.w, s2);
            nacc[i] += s2;
        }
        if (kc < 3) {
#pragma unroll
            for (int i = 0; i < 4; ++i) {
                const float* src = V + (size_t)stok[mrow + i * 16] * PP + (kc + 1) * 128 + f * 8;
                pa[i][0] = ((const float4*)src)[0];
                pa[i][1] = ((const float4*)src)[1];
            }
        } else {
#pragma unroll
            for (int i = 0; i < 4; ++i) {
                float r = nacc[i];
                r += __shfl_down(r, 8, 16);
                r += __shfl_down(r, 4, 16);
                r += __shfl_down(r, 2, 16);
                r += __shfl_down(r, 1, 16);
                if (f == 0) rnorm[mrow + i * 16] = rsqrtf(r);
            }
        }
        __syncthreads();

        // ---- MFMA: 8 K-steps of 16; B straight from global (L1/L2-hot) ----
#pragma unroll
        for (int kb = 0; kb < 8; ++kb) {
            const int ff = kb * 2 + (lane >> 5);
            const int mq = mt + (lane & 31);
            const uint4 av = sA[mq * 16 + (ff ^ (mq & 7))];
            const uint4 b0 = Bu4[(kc * 16 + ff) * 128 + nh + (lane & 31)];
            const uint4 b1 = Bu4[(kc * 16 + ff) * 128 + nh + 32 + (lane & 31)];
            short8 a8, t0, t1;
            __builtin_memcpy(&a8, &av, 16);
            __builtin_memcpy(&t0, &b0, 16);
            __builtin_memcpy(&t1, &b1, 16);
            acc0 = __builtin_amdgcn_mfma_f32_32x32x16_bf16(a8, t0, acc0, 0, 0, 0);
            acc1 = __builtin_amdgcn_mfma_f32_32x32x16_bf16(a8, t1, acc1, 0, 0, 0);
        }
    }

    // ---- epilogue: pack (j, j+32) bf16 pairs ----
    const size_t posBase = (size_t)blockIdx.x * 64;
#pragma unroll
    for (int reg = 0; reg < 16; ++reg) {
        const int r  = (reg & 3) + 8 * (reg >> 2) + 4 * (lane >> 5);
        const int mq = mt + r;
        const size_t p = posBase + mq;
        if (wv < 2) {
            const float rn = rnorm[mq];
            Gt2[p * 32 + (lane & 31)] = pack_bf2(acc0[reg] * rn, acc1[reg] * rn);
        } else {
            E2p[p * 32 + (lane & 31)] = pack_bf2(acc0[reg], acc1[reg]);
        }
    }
}

// ---------------------------------------------------------------------------
// K3: fused conv-max + online-softmax partial pooling. Block = (b, 64-l tile),
// 1024 blocks.  pool[blk][0..63]=P_c, [64]=mx_c, [65]=se_c (stride 68)
// ---------------------------------------------------------------------------
__global__ void k3_convpool(const unsigned int* __restrict__ Gt2,
                            const unsigned int* __restrict__ E2p,
                            const float* __restrict__ f1w, const float* __restrict__ f1b,
                            float* __restrict__ pool) {
    __shared__ unsigned int sT[74 * 33];   // 9.5 KB
    __shared__ float smv[64];
    __shared__ float sp[64];
    __shared__ float sscal[2];
    __shared__ float sred[8][64];

    const int b  = blockIdx.x >> 5;
    const int l0 = (blockIdx.x & 31) * 64;
    const int t  = threadIdx.x;

    for (int idx = t; idx < 74 * 32; idx += 256) {
        const int row = idx >> 5, col = idx & 31;
        const int gl = l0 - 5 + row;
        sT[row * 33 + col] = (gl >= 0 && gl < LLEN)
            ? Gt2[((size_t)b * LLEN + gl) * 32 + col] : 0u;
    }
    __syncthreads();

    float w[11];
#pragma unroll
    for (int j = 0; j < 11; ++j) w[j] = f1w[j];
    const int j = t & 31;
    const int h = t >> 5;                  // 0..7
    const float bias0 = f1b[j], bias1 = f1b[j + 32];
#pragma unroll
    for (int i = 0; i < 8; ++i) {
        const int lr = i * 8 + h;          // 0..63
        float u0 = 0.f, u1 = 0.f;
#pragma unroll
        for (int tap = 0; tap < 11; ++tap) {
            const unsigned int v = sT[(lr + tap) * 33 + j];
            u0 = fmaf(bf_lo(v), w[tap], u0);
            u1 = fmaf(bf_hi(v), w[tap], u1);
        }
        float m = fmaxf(fmaxf(u0 + bias0, 0.f), fmaxf(u1 + bias1, 0.f));
#pragma unroll
        for (int off = 16; off > 0; off >>= 1)
            m = fmaxf(m, __shfl_xor(m, off, 64));
        if (j == 0) smv[lr] = m;
    }
    __syncthreads();

    if (t < 64) {
        float v = smv[t];
#pragma unroll
        for (int off = 32; off > 0; off >>= 1)
            v = fmaxf(v, __shfl_xor(v, off, 64));
        if (t == 0) sscal[0] = v;
    }
    __syncthreads();
    const float mx = sscal[0];
    if (t < 64) sp[t] = __expf(smv[t] - mx);
    __syncthreads();
    if (t < 64) {
        float s = sp[t];
#pragma unroll
        for (int off = 32; off > 0; off >>= 1)
            s += __shfl_xor(s, off, 64);
        if (t == 0) sscal[1] = s;
    }

    // partial pooling over the 64 l of this tile
    float a0 = 0.f, a1 = 0.f;
#pragma unroll
    for (int i = 0; i < 8; ++i) {
        const int l = i * 8 + h;
        const float wgt = sp[l];
        const unsigned int e = E2p[((size_t)b * LLEN + l0 + l) * 32 + j];
        a0 = fmaf(wgt, bf_lo(e), a0);
        a1 = fmaf(wgt, bf_hi(e), a1);
    }
    sred[h][j]      = a0;
    sred[h][j + 32] = a1;
    __syncthreads();
    if (t < 64) {
        float r = 0.f;
#pragma unroll
        for (int hh = 0; hh < 8; ++hh) r += sred[hh][t];
        float* dst = pool + (size_t)blockIdx.x * 68;
        dst[t] = r;
        if (t == 0) { dst[64] = sscal[0]; dst[65] = sscal[1]; }
    }
}

// ---------------------------------------------------------------------------
// K6: combine 32 chunk-partials per b with online-softmax rescale + head bias.
// ---------------------------------------------------------------------------
__global__ void k6_final(const float* __restrict__ pool, const float* __restrict__ f2b,
                         float* __restrict__ out) {
    const int b = blockIdx.x;
    const int k = threadIdx.x;   // 64 threads
    float M = -1e30f;
#pragma unroll
    for (int c = 0; c < 32; ++c)
        M = fmaxf(M, pool[(size_t)(b * 32 + c) * 68 + 64]);
    float tot = 0.f, num = 0.f;
#pragma unroll
    for (int c = 0; c < 32; ++c) {
        const float* pc = pool + (size_t)(b * 32 + c) * 68;
        const float sc = __expf(pc[64] - M);
        tot = fmaf(sc, pc[65], tot);
        num = fmaf(sc, pc[k], num);
    }
    out[b * KK + k] = (num / tot) * (1.f / 2048.f) + f2b[k];
}

extern "C" void kernel_launch(void* const* d_in, const int* in_sizes, int n_in,
                              void* d_out, int out_size, void* d_ws, size_t ws_size,
                              hipStream_t stream) {
    const int*   x   = (const int*)d_in[0];
    const float* V   = (const float*)d_in[1];
    const float* C   = (const float*)d_in[2];
    const float* f1w = (const float*)d_in[3];
    const float* f1b = (const float*)d_in[4];
    const float* f2w = (const float*)d_in[5];
    const float* f2b = (const float*)d_in[6];
    float* out = (float*)d_out;

    float* ws = (float*)d_ws;
    ushort* Bu = (ushort*)ws;                             // 65536 ushort = 32768 floats
    unsigned int* Gt2 = (unsigned int*)(ws + 32768);      // NPOS*32 uints
    unsigned int* E2p = Gt2 + (size_t)NPOS * 32;          // NPOS*32 uints
    float* pool = (float*)(E2p + (size_t)NPOS * 32);      // 1024*68 floats

    k1_prep    <<<128, 256, 0, stream>>>(C, f2w, Bu);
    k2_gemm    <<<NPOS / 64, 256, 0, stream>>>(x, V, (const uint4*)Bu, Gt2, E2p);
    k3_convpool<<<BB * 32, 256, 0, stream>>>(Gt2, E2p, f1w, f1b, pool);
    k6_final   <<<BB, 64, 0, stream>>>(pool, f2b, out);
}

// Round 7
// 190.305 us; speedup vs baseline: 1.1010x; 1.0445x over previous
//
#include <hip/hip_runtime.h>
#include <hip/hip_bf16.h>

#define PP     512
#define KK     64
#define BB     32
#define LLEN   2048
#define NPOS   (BB * LLEN)   // 65536

typedef __attribute__((ext_vector_type(8)))  short short8;
typedef __attribute__((ext_vector_type(16))) float float16;

__device__ inline unsigned int pack_bf2(float lo, float hi) {
    __hip_bfloat162 h = __float22bfloat162_rn(make_float2(lo, hi));
    unsigned int u;
    __builtin_memcpy(&u, &h, 4);
    return u;   // low 16 = lo, high 16 = hi
}
__device__ inline float bf_lo(unsigned int v) { return __uint_as_float(v << 16); }
__device__ inline float bf_hi(unsigned int v) { return __uint_as_float(v & 0xffff0000u); }

// ---------------------------------------------------------------------------
// K1: unified B-operand fragments, 128 cols: n<64 -> l_hat[n], n>=64 -> f2w[n-64].
// Bu4[f*128 + n] = 8 bf16 of src[n][8f..8f+7] (f = 0..63).
// ---------------------------------------------------------------------------
__global__ void k1_prep(const float* __restrict__ C, const float* __restrict__ f2w,
                        ushort* __restrict__ Bu) {
    const int n = blockIdx.x;            // 0..127
    const float* src = (n < 64) ? (C + n * PP) : (f2w + (n - 64) * PP);
    const int t = threadIdx.x;
    float v0 = src[t];
    float v1 = src[t + 256];
    __shared__ float red[256];
    red[t] = v0 * v0 + v1 * v1;
    __syncthreads();
    for (int s = 128; s > 0; s >>= 1) {
        if (t < s) red[t] += red[t + s];
        __syncthreads();
    }
    const float inv = (n < 64) ? rsqrtf(red[0]) : 1.f;
    Bu[(((t >> 3)       * 128 + n) << 3) + (t & 7)] = (ushort)(pack_bf2(v0 * inv, 0.f) & 0xffffu);
    Bu[((((t + 256) >> 3)) * 128 + n) * 8 + (t & 7)] = (ushort)(pack_bf2(v1 * inv, 0.f) & 0xffffu);
}

// ---------------------------------------------------------------------------
// K2: MFMA GEMM, 64 pos x 128 cols, SINGLE staging phase (max MLP):
// each thread gathers 32 float4 (one V row quarter-interleave) back-to-back,
// packs bf16 8-B halves into xor-swizzled LDS; ONE barrier; 32 MFMA k-steps
// with B direct from global (L1-hot). LDS 64.5 KB -> 2 blocks/CU.
// ---------------------------------------------------------------------------
__launch_bounds__(256)
__global__ void k2_gemm(const int* __restrict__ x, const float* __restrict__ V,
                        const uint4* __restrict__ Bu4,
                        unsigned int* __restrict__ Gt2, unsigned int* __restrict__ E2p) {
    __shared__ uint4 sA[64 * 64];    // 64 KB: row m stride 64 frags, frag f at (f ^ (m&7))
    __shared__ int   stok[64];
    __shared__ float rnorm[64];

    const int tid  = threadIdx.x;
    const int lane = tid & 63;
    const int wv   = tid >> 6;
    const int r    = tid >> 2;       // 0..63: row this thread stages
    const int q    = tid & 3;        // quarter-interleave within row

    if (tid < 64) stok[tid] = x[blockIdx.x * 64 + tid];
    __syncthreads();

    // ---- staging: 32 x 16B loads/thread, grouped 2x16, then pack ----
    const float* src = V + (size_t)stok[r] * PP + q * 4;   // +g*16 floats per load
    const int swzr = r & 7;
    float nrm = 0.f;

    float4 pa[16];
#pragma unroll
    for (int g = 0; g < 16; ++g) pa[g] = ((const float4*)src)[g * 4];
    float4 pb[16];
#pragma unroll
    for (int g = 0; g < 16; ++g) pb[g] = ((const float4*)src)[(g + 16) * 4];

#pragma unroll
    for (int g = 0; g < 16; ++g) {
        const float4 a = pa[g];
        nrm = fmaf(a.x, a.x, fmaf(a.y, a.y, fmaf(a.z, a.z, fmaf(a.w, a.w, nrm))));
        uint2 w2; w2.x = pack_bf2(a.x, a.y); w2.y = pack_bf2(a.z, a.w);
        const int f = g * 2 + (q >> 1);
        ((uint2*)&sA[r * 64 + (f ^ swzr)])[q & 1] = w2;
    }
#pragma unroll
    for (int g = 0; g < 16; ++g) {
        const float4 a = pb[g];
        nrm = fmaf(a.x, a.x, fmaf(a.y, a.y, fmaf(a.z, a.z, fmaf(a.w, a.w, nrm))));
        uint2 w2; w2.x = pack_bf2(a.x, a.y); w2.y = pack_bf2(a.z, a.w);
        const int f = (g + 16) * 2 + (q >> 1);
        ((uint2*)&sA[r * 64 + (f ^ swzr)])[q & 1] = w2;
    }

    // per-row norm: reduce across the 4 lanes of the quad (same row)
    nrm += __shfl_xor(nrm, 1, 64);
    nrm += __shfl_xor(nrm, 2, 64);
    if (q == 0) rnorm[r] = rsqrtf(nrm);
    __syncthreads();

    // ---- MFMA: 32 k-steps of 16; B from global ----
    float16 acc0, acc1;
#pragma unroll
    for (int i = 0; i < 16; ++i) { acc0[i] = 0.f; acc1[i] = 0.f; }

    const int mt  = (wv & 1) * 32;
    const int nh  = (wv >> 1) * 64;     // waves 0,1 -> cos (cols 0-63); 2,3 -> E2 (64-127)
    const int l31 = lane & 31;
    const int cc  = lane >> 5;
    const int mq  = mt + l31;
    const int abase = mq * 64;
    const int aswz  = mq & 7;

#pragma unroll 8
    for (int ks = 0; ks < 32; ++ks) {
        const int ff = ks * 2 + cc;
        const uint4 av = sA[abase + (ff ^ aswz)];
        const uint4 b0 = Bu4[ff * 128 + nh + l31];
        const uint4 b1 = Bu4[ff * 128 + nh + 32 + l31];
        short8 a8, t0, t1;
        __builtin_memcpy(&a8, &av, 16);
        __builtin_memcpy(&t0, &b0, 16);
        __builtin_memcpy(&t1, &b1, 16);
        acc0 = __builtin_amdgcn_mfma_f32_32x32x16_bf16(a8, t0, acc0, 0, 0, 0);
        acc1 = __builtin_amdgcn_mfma_f32_32x32x16_bf16(a8, t1, acc1, 0, 0, 0);
    }

    // ---- epilogue: pack (j, j+32) bf16 pairs ----
    const size_t posBase = (size_t)blockIdx.x * 64;
#pragma unroll
    for (int reg = 0; reg < 16; ++reg) {
        const int rr = (reg & 3) + 8 * (reg >> 2) + 4 * (lane >> 5);
        const int m  = mt + rr;
        const size_t p = posBase + m;
        if (wv < 2) {
            const float rn = rnorm[m];
            Gt2[p * 32 + l31] = pack_bf2(acc0[reg] * rn, acc1[reg] * rn);
        } else {
            E2p[p * 32 + l31] = pack_bf2(acc0[reg], acc1[reg]);
        }
    }
}

// ---------------------------------------------------------------------------
// K3: fused conv-max + online-softmax partial pooling. Block = (b, 64-l tile),
// 1024 blocks.  pool[blk][0..63]=P_c, [64]=mx_c, [65]=se_c (stride 68)
// ---------------------------------------------------------------------------
__global__ void k3_convpool(const unsigned int* __restrict__ Gt2,
                            const unsigned int* __restrict__ E2p,
                            const float* __restrict__ f1w, const float* __restrict__ f1b,
                            float* __restrict__ pool) {
    __shared__ unsigned int sT[74 * 33];   // 9.5 KB
    __shared__ float smv[64];
    __shared__ float sp[64];
    __shared__ float sscal[2];
    __shared__ float sred[8][64];

    const int b  = blockIdx.x >> 5;
    const int l0 = (blockIdx.x & 31) * 64;
    const int t  = threadIdx.x;

    for (int idx = t; idx < 74 * 32; idx += 256) {
        const int row = idx >> 5, col = idx & 31;
        const int gl = l0 - 5 + row;
        sT[row * 33 + col] = (gl >= 0 && gl < LLEN)
            ? Gt2[((size_t)b * LLEN + gl) * 32 + col] : 0u;
    }
    __syncthreads();

    float w[11];
#pragma unroll
    for (int j = 0; j < 11; ++j) w[j] = f1w[j];
    const int j = t & 31;
    const int h = t >> 5;                  // 0..7
    const float bias0 = f1b[j], bias1 = f1b[j + 32];
#pragma unroll
    for (int i = 0; i < 8; ++i) {
        const int lr = i * 8 + h;          // 0..63
        float u0 = 0.f, u1 = 0.f;
#pragma unroll
        for (int tap = 0; tap < 11; ++tap) {
            const unsigned int v = sT[(lr + tap) * 33 + j];
            u0 = fmaf(bf_lo(v), w[tap], u0);
            u1 = fmaf(bf_hi(v), w[tap], u1);
        }
        float m = fmaxf(fmaxf(u0 + bias0, 0.f), fmaxf(u1 + bias1, 0.f));
#pragma unroll
        for (int off = 16; off > 0; off >>= 1)
            m = fmaxf(m, __shfl_xor(m, off, 64));
        if (j == 0) smv[lr] = m;
    }
    __syncthreads();

    if (t < 64) {
        float v = smv[t];
#pragma unroll
        for (int off = 32; off > 0; off >>= 1)
            v = fmaxf(v, __shfl_xor(v, off, 64));
        if (t == 0) sscal[0] = v;
    }
    __syncthreads();
    const float mx = sscal[0];
    if (t < 64) sp[t] = __expf(smv[t] - mx);
    __syncthreads();
    if (t < 64) {
        float s = sp[t];
#pragma unroll
        for (int off = 32; off > 0; off >>= 1)
            s += __shfl_xor(s, off, 64);
        if (t == 0) sscal[1] = s;
    }

    float a0 = 0.f, a1 = 0.f;
#pragma unroll
    for (int i = 0; i < 8; ++i) {
        const int l = i * 8 + h;
        const float wgt = sp[l];
        const unsigned int e = E2p[((size_t)b * LLEN + l0 + l) * 32 + j];
        a0 = fmaf(wgt, bf_lo(e), a0);
        a1 = fmaf(wgt, bf_hi(e), a1);
    }
    sred[h][j]      = a0;
    sred[h][j + 32] = a1;
    __syncthreads();
    if (t < 64) {
        float r = 0.f;
#pragma unroll
        for (int hh = 0; hh < 8; ++hh) r += sred[hh][t];
        float* dst = pool + (size_t)blockIdx.x * 68;
        dst[t] = r;
        if (t == 0) { dst[64] = sscal[0]; dst[65] = sscal[1]; }
    }
}

// ---------------------------------------------------------------------------
// K6: combine 32 chunk-partials per b with online-softmax rescale + head bias.
// ---------------------------------------------------------------------------
__global__ void k6_final(const float* __restrict__ pool, const float* __restrict__ f2b,
                         float* __restrict__ out) {
    const int b = blockIdx.x;
    const int k = threadIdx.x;   // 64 threads
    float M = -1e30f;
#pragma unroll
    for (int c = 0; c < 32; ++c)
        M = fmaxf(M, pool[(size_t)(b * 32 + c) * 68 + 64]);
    float tot = 0.f, num = 0.f;
#pragma unroll
    for (int c = 0; c < 32; ++c) {
        const float* pc = pool + (size_t)(b * 32 + c) * 68;
        const float sc = __expf(pc[64] - M);
        tot = fmaf(sc, pc[65], tot);
        num = fmaf(sc, pc[k], num);
    }
    out[b * KK + k] = (num / tot) * (1.f / 2048.f) + f2b[k];
}

extern "C" void kernel_launch(void* const* d_in, const int* in_sizes, int n_in,
                              void* d_out, int out_size, void* d_ws, size_t ws_size,
                              hipStream_t stream) {
    const int*   x   = (const int*)d_in[0];
    const float* V   = (const float*)d_in[1];
    const float* C   = (const float*)d_in[2];
    const float* f1w = (const float*)d_in[3];
    const float* f1b = (const float*)d_in[4];
    const float* f2w = (const float*)d_in[5];
    const float* f2b = (const float*)d_in[6];
    float* out = (float*)d_out;

    float* ws = (float*)d_ws;
    ushort* Bu = (ushort*)ws;                             // 65536 ushort
    unsigned int* Gt2 = (unsigned int*)(ws + 32768);      // NPOS*32 uints
    unsigned int* E2p = Gt2 + (size_t)NPOS * 32;          // NPOS*32 uints
    float* pool = (float*)(E2p + (size_t)NPOS * 32);      // 1024*68 floats

    k1_prep    <<<128, 256, 0, stream>>>(C, f2w, Bu);
    k2_gemm    <<<NPOS / 64, 256, 0, stream>>>(x, V, (const uint4*)Bu, Gt2, E2p);
    k3_convpool<<<BB * 32, 256, 0, stream>>>(Gt2, E2p, f1w, f1b, pool);
    k6_final   <<<BB, 64, 0, stream>>>(pool, f2b, out);
}